// Round 2
// 377.824 us; speedup vs baseline: 1.0683x; 1.0683x over previous
//
#include <hip/hip_runtime.h>
#include <cstdint>
#include <cstddef>

#define B_ 32
#define N_ 512
#define H_ 256
#define S_ 3
#define BN_ (B_*N_)            // 16384
#define HH_ (H_*H_)            // 65536
#define BIGF 3.4028234e+38f
#define EPSF 1e-5f

typedef __bf16 bf16x8 __attribute__((ext_vector_type(8)));
typedef float  f32x4  __attribute__((ext_vector_type(4)));

typedef const void __attribute__((address_space(1)))* gas_t;
typedef void __attribute__((address_space(3)))* las_t;

// async global->LDS, 16B per lane. LDS dest must be wave-uniform base + lane*16.
__device__ __forceinline__ void async16(const unsigned short* g, unsigned short* l) {
  __builtin_amdgcn_global_load_lds((gas_t)g, (las_t)l, 16, 0, 0);
}

__device__ __forceinline__ unsigned short f2bf(float f) {
  __bf16 h = (__bf16)f;
  unsigned short s;
  __builtin_memcpy(&s, &h, 2);
  return s;
}
__device__ __forceinline__ float bf2f(unsigned short u) {
  unsigned int v = ((unsigned int)u) << 16;
  float f;
  __builtin_memcpy(&f, &v, 4);
  return f;
}

// XOR-swizzle for 32-short (64B) LDS rows, 4 chunks of 8 shorts.
#define KC_STAGE(lane) ((((lane) & 3) ^ (((lane) >> 3) & 3)) * 8)
#define KC_READ(quad, l15) ((((quad) ^ (((l15) >> 1) & 3))) * 8)

// ------------- all 5 weight tensors -> bf16 in one dispatch -------------
__global__ __launch_bounds__(256) void cvt_all_k(
    const float* __restrict__ WQ, const float* __restrict__ WK,
    const float* __restrict__ WV, const float* __restrict__ W1,
    const float* __restrict__ W2,
    unsigned short* __restrict__ wqk, unsigned short* __restrict__ wv,
    unsigned short* __restrict__ w1, unsigned short* __restrict__ w2) {
  const int per = S_ * HH_ / 4;
  int gi = blockIdx.x * 256 + threadIdx.x;
  int which = gi / per;
  int e4 = gi - which * per;
  float4 v;
  if      (which == 0) v = ((const float4*)WQ)[e4];
  else if (which == 1) v = ((const float4*)WK)[e4];
  else if (which == 2) v = ((const float4*)WV)[e4];
  else if (which == 3) v = ((const float4*)W1)[e4];
  else                 v = ((const float4*)W2)[e4];
  ushort4 o;
  o.x = f2bf(v.x); o.y = f2bf(v.y); o.z = f2bf(v.z); o.w = f2bf(v.w);
  int e = e4 * 4;
  if (which <= 1) {
    int L = e / HH_, off = e - L * HH_;
    *(ushort4*)&wqk[(size_t)L * 2 * HH_ + (which == 1 ? HH_ : 0) + off] = o;
  } else if (which == 2) ((ushort4*)wv)[e4] = o;
  else if   (which == 3) ((ushort4*)w1)[e4] = o;
  else                   ((ushort4*)w2)[e4] = o;
}

// ------------- f_bf = bf16(x * mask_row) -------------
__global__ __launch_bounds__(256) void mask_mul_k(
    const float* __restrict__ x, const float* __restrict__ masks,
    unsigned short* __restrict__ fb) {
  int i = blockIdx.x * 256 + threadIdx.x;
  int row = i >> 6;
  float m = masks[row];
  float4 v = ((const float4*)x)[i];
  ushort4 o;
  o.x = f2bf(v.x * m); o.y = f2bf(v.y * m); o.z = f2bf(v.z * m); o.w = f2bf(v.w * m);
  ((ushort4*)fb)[i] = o;
}

// ================= MFMA GEMM (128x128, BK=32, dbuf prefetch, 1 barrier/step), bf16 out =================
// C = A(bf16,[m][k],lda) @ B(bf16,[n][k],ldb)^T
__global__ __launch_bounds__(256) void mfma_gemm_k(
    const unsigned short* __restrict__ A, const unsigned short* __restrict__ Bm,
    unsigned short* __restrict__ Cb,
    int K, int Nn, int lda, int ldb, long sA, long sB, long sC) {
  __shared__ __align__(16) unsigned short As[2][128 * 32];
  __shared__ __align__(16) unsigned short Bs[2][128 * 32];
  const int b = blockIdx.z;
  const int t = threadIdx.x;
  const int wave = t >> 6, lane = t & 63;
  const int wm = wave >> 1, wn = wave & 1;
  const int quad = lane >> 4, l15 = lane & 15;
  const int m0 = blockIdx.y * 128, n0 = blockIdx.x * 128;
  const int srow = lane >> 2;
  const int kc = KC_STAGE(lane);
  const int pos8 = (lane & 3) * 8;

  const unsigned short* pa0 = A + (size_t)b * sA + (size_t)(m0 + wave * 32 + srow) * lda + kc;
  const unsigned short* pa1 = pa0 + 16 * (size_t)lda;
  const unsigned short* pb0 = Bm + (size_t)b * sB + (size_t)(n0 + wave * 32 + srow) * ldb + kc;
  const unsigned short* pb1 = pb0 + 16 * (size_t)ldb;
  const int lo = (wave * 32 + srow) * 32 + pos8;

  f32x4 acc[4][4];
#pragma unroll
  for (int i = 0; i < 4; ++i)
#pragma unroll
    for (int j = 0; j < 4; ++j) acc[i][j] = (f32x4){0.f, 0.f, 0.f, 0.f};

  const int soff = KC_READ(quad, l15);
  const int NT = K >> 5;
  // prologue: stage tile 0 into buffer 0
  async16(pa0, &As[0][lo]); async16(pa1, &As[0][lo + 16 * 32]);
  async16(pb0, &Bs[0][lo]); async16(pb1, &Bs[0][lo + 16 * 32]);
  __syncthreads();
  int cur = 0;
  for (int tt = 0; tt < NT; ++tt) {
    if (tt + 1 < NT) {                 // issue next tile before consuming current
      const int kn = (tt + 1) << 5;
      async16(pa0 + kn, &As[cur ^ 1][lo]); async16(pa1 + kn, &As[cur ^ 1][lo + 16 * 32]);
      async16(pb0 + kn, &Bs[cur ^ 1][lo]); async16(pb1 + kn, &Bs[cur ^ 1][lo + 16 * 32]);
    }
    bf16x8 af[4], bfr[4];
#pragma unroll
    for (int i = 0; i < 4; ++i)
      af[i] = *(const bf16x8*)&As[cur][(wm * 64 + i * 16 + l15) * 32 + soff];
#pragma unroll
    for (int j = 0; j < 4; ++j)
      bfr[j] = *(const bf16x8*)&Bs[cur][(wn * 64 + j * 16 + l15) * 32 + soff];
#pragma unroll
    for (int i = 0; i < 4; ++i)
#pragma unroll
      for (int j = 0; j < 4; ++j)
        acc[i][j] = __builtin_amdgcn_mfma_f32_16x16x32_bf16(af[i], bfr[j], acc[i][j], 0, 0, 0);
    __syncthreads();                   // drains vmcnt: next tile ready; all reads of cur done
    cur ^= 1;
  }

#pragma unroll
  for (int i = 0; i < 4; ++i) {
    const int rbase = m0 + wm * 64 + i * 16 + quad * 4;
#pragma unroll
    for (int j = 0; j < 4; ++j) {
      const int c = n0 + wn * 64 + j * 16 + l15;
#pragma unroll
      for (int r = 0; r < 4; ++r)
        Cb[(size_t)b * sC + (size_t)(rbase + r) * Nn + c] = f2bf(acc[i][j][r]);
    }
  }
}

// ========== Fused [QK^T + mask/guide + softmax | prior-copy] + P@V^T + residual + LN ==========
// 64 q-rows per block, 512 threads (8 waves). PRIOR=1: P comes from prior (layer 0).
// Grid (B, N/64): batch on blockIdx.x so all 8 q-tiles of a batch share an XCD (L2 reuse of K/V).
// Both K-loops: double-buffered LDS, prefetch next tile, ONE barrier per step.
template<int PRIOR>
__global__ __launch_bounds__(512) void ls_pv_k(
    const unsigned short* __restrict__ qk, const float* __restrict__ prior,
    const float* __restrict__ masks, const float* __restrict__ guide,
    const unsigned short* __restrict__ vT, const unsigned short* __restrict__ resb,
    float* __restrict__ att, float* __restrict__ post, unsigned short* __restrict__ postb) {
  __shared__ __align__(16) unsigned short As[2][64 * 32];     // 8 KB
  __shared__ __align__(16) unsigned short Bs[2][512 * 32];    // 64 KB (phase B uses first 256 rows/buf)
  __shared__ __align__(16) unsigned short Ps[64 * 520];       // 66.5 KB, padded rows
  __shared__ float red[4][64][2];                             // 2 KB
  const int b = blockIdx.x;
  const int t = threadIdx.x;
  const int wave = t >> 6, lane = t & 63;
  const int quad = lane >> 4, l15 = lane & 15;
  const int m0 = blockIdx.y * 64;
  const int srow = lane >> 2;
  const int kc = KC_STAGE(lane);
  const int pos8 = (lane & 3) * 8;
  const int soff = KC_READ(quad, l15);

  // Phase-B V staging pointers (declared early for cross-phase prefetch)
  const unsigned short* vb = vT + (size_t)b * H_ * N_;
  const unsigned short* pv0 = vb + (size_t)(wave * 16 + srow) * N_ + kc;  // rows 0..127
  const unsigned short* pv1 = pv0 + (size_t)128 * N_;                     // rows 128..255
  const int lvo = (wave * 16 + srow) * 32 + pos8;

  if (PRIOR) {
    // early V tile-0 prefetch (Bs unused by phase A'): hidden under the prior copy
    async16(pv0, &Bs[0][lvo]);
    async16(pv1, &Bs[0][lvo + 128 * 32]);
    // ---- Phase A': copy prior -> att out, convert -> Ps ----
    const float* src = prior + ((size_t)b * N_ + m0) * N_;
    float*       dst = att   + ((size_t)b * N_ + m0) * N_;
#pragma unroll
    for (int s = 0; s < 16; ++s) {
      int idx4 = s * 512 + t;
      float4 v = ((const float4*)src)[idx4];
      ((float4*)dst)[idx4] = v;
      int row = idx4 >> 7, col4 = idx4 & 127;
      ushort4 o;
      o.x = f2bf(v.x); o.y = f2bf(v.y); o.z = f2bf(v.z); o.w = f2bf(v.w);
      *(ushort4*)&Ps[row * 520 + col4 * 4] = o;
    }
    __syncthreads();   // Ps visible + V tile-0 staged (vmcnt drained)
  } else {
    // ---- Phase A: QK^T ----
    const int wm = wave >> 2, wn = wave & 3;
    const int ld = 2 * H_;
    const unsigned short* base = qk + (size_t)b * N_ * ld;
    const unsigned short* pa = base + (size_t)(m0 + wave * 16 + srow) * ld + kc;   // waves 0..3
    const unsigned short* pb = base + H_ + (size_t)(wave * 64 + srow) * ld + kc;
    const int lao = (wave * 16 + srow) * 32 + pos8;
    const int lbo = (wave * 64 + srow) * 32 + pos8;

    f32x4 acc[2][8];
#pragma unroll
    for (int i = 0; i < 2; ++i)
#pragma unroll
      for (int j = 0; j < 8; ++j) acc[i][j] = (f32x4){0.f, 0.f, 0.f, 0.f};

    // prologue: tile 0 -> buffer 0
    if (wave < 4) async16(pa, &As[0][lao]);
#pragma unroll
    for (int c = 0; c < 4; ++c)
      async16(pb + (size_t)c * 16 * ld, &Bs[0][lbo + c * 16 * 32]);
    __syncthreads();
    int cur = 0;
#pragma unroll
    for (int tt = 0; tt < 8; ++tt) {
      if (tt < 7) {
        const int kn = (tt + 1) * 32;
        if (wave < 4) async16(pa + kn, &As[cur ^ 1][lao]);
#pragma unroll
        for (int c = 0; c < 4; ++c)
          async16(pb + (size_t)c * 16 * ld + kn, &Bs[cur ^ 1][lbo + c * 16 * 32]);
      }
      bf16x8 af[2], bfr[8];
#pragma unroll
      for (int i = 0; i < 2; ++i)
        af[i] = *(const bf16x8*)&As[cur][(wm * 32 + i * 16 + l15) * 32 + soff];
#pragma unroll
      for (int j = 0; j < 8; ++j)
        bfr[j] = *(const bf16x8*)&Bs[cur][(wn * 128 + j * 16 + l15) * 32 + soff];
#pragma unroll
      for (int i = 0; i < 2; ++i)
#pragma unroll
        for (int j = 0; j < 8; ++j)
          acc[i][j] = __builtin_amdgcn_mfma_f32_16x16x32_bf16(af[i], bfr[j], acc[i][j], 0, 0, 0);
      __syncthreads();
      cur ^= 1;
    }

    // early V tile-0 prefetch: all phase-A reads of Bs are behind the last barrier;
    // the load is hidden under the 3-pass softmax below.
    async16(pv0, &Bs[0][lvo]);
    async16(pv1, &Bs[0][lvo + 128 * 32]);

    // logits + row-max
    float am[8];
#pragma unroll
    for (int j = 0; j < 8; ++j) {
      float mv = masks[(size_t)b * N_ + wn * 128 + j * 16 + l15];
      am[j] = (mv != 0.f) ? 0.f : BIGF;
    }
#pragma unroll
    for (int i = 0; i < 2; ++i) {
#pragma unroll
      for (int r = 0; r < 4; ++r) {
        const int mloc = wm * 32 + i * 16 + quad * 4 + r;
        const float* gr = guide + ((size_t)b * N_ + m0 + mloc) * N_;
        float mx = -BIGF;
#pragma unroll
        for (int j = 0; j < 8; ++j) {
          const int c = wn * 128 + j * 16 + l15;
          float g = gr[c];
          float v = acc[i][j][r] * 0.0625f - am[j] - ((g != 0.f) ? 0.f : BIGF);
          acc[i][j][r] = v;
          mx = fmaxf(mx, v);
        }
#pragma unroll
        for (int off = 1; off < 16; off <<= 1) mx = fmaxf(mx, __shfl_xor(mx, off));
        if (l15 == 0) red[wn][mloc][0] = mx;
      }
    }
    __syncthreads();
    // exp + row-sum
#pragma unroll
    for (int i = 0; i < 2; ++i) {
#pragma unroll
      for (int r = 0; r < 4; ++r) {
        const int mloc = wm * 32 + i * 16 + quad * 4 + r;
        float M = fmaxf(fmaxf(red[0][mloc][0], red[1][mloc][0]),
                        fmaxf(red[2][mloc][0], red[3][mloc][0]));
        float s = 0.f;
#pragma unroll
        for (int j = 0; j < 8; ++j) {
          float e = __expf(acc[i][j][r] - M);
          acc[i][j][r] = e;
          s += e;
        }
#pragma unroll
        for (int off = 1; off < 16; off <<= 1) s += __shfl_xor(s, off);
        if (l15 == 0) red[wn][mloc][1] = s;
      }
    }
    __syncthreads();
    // normalize -> att fp32 + Ps bf16
#pragma unroll
    for (int i = 0; i < 2; ++i) {
#pragma unroll
      for (int r = 0; r < 4; ++r) {
        const int mloc = wm * 32 + i * 16 + quad * 4 + r;
        float S = red[0][mloc][1] + red[1][mloc][1] + red[2][mloc][1] + red[3][mloc][1];
        float inv = 1.f / S;
        const size_t rowoff = ((size_t)b * N_ + m0 + mloc) * N_;
#pragma unroll
        for (int j = 0; j < 8; ++j) {
          const int c = wn * 128 + j * 16 + l15;
          float o = acc[i][j][r] * inv;
          att[rowoff + c] = o;
          Ps[mloc * 520 + c] = f2bf(o);
        }
      }
    }
    __syncthreads();   // Ps visible + V tile-0 staged (vmcnt drained)
  }

  // ---- Phase B: post = LN(P @ vT^T + f) ----
  const int wm2 = wave >> 2, wn2 = wave & 3;

  f32x4 acc2[2][4];
#pragma unroll
  for (int i = 0; i < 2; ++i)
#pragma unroll
    for (int j = 0; j < 4; ++j) acc2[i][j] = (f32x4){0.f, 0.f, 0.f, 0.f};

  int cur = 0;   // V tile 0 already staged in Bs[0]
#pragma unroll
  for (int tt = 0; tt < 16; ++tt) {
    if (tt < 15) {
      const int kn = (tt + 1) * 32;
      async16(pv0 + kn, &Bs[cur ^ 1][lvo]);
      async16(pv1 + kn, &Bs[cur ^ 1][lvo + 128 * 32]);
    }
    bf16x8 af[2], bfr[4];
#pragma unroll
    for (int i = 0; i < 2; ++i)
      af[i] = *(const bf16x8*)&Ps[(wm2 * 32 + i * 16 + l15) * 520 + tt * 32 + quad * 8];
#pragma unroll
    for (int j = 0; j < 4; ++j)
      bfr[j] = *(const bf16x8*)&Bs[cur][(wn2 * 64 + j * 16 + l15) * 32 + soff];
#pragma unroll
    for (int i = 0; i < 2; ++i)
#pragma unroll
      for (int j = 0; j < 4; ++j)
        acc2[i][j] = __builtin_amdgcn_mfma_f32_16x16x32_bf16(af[i], bfr[j], acc2[i][j], 0, 0, 0);
    __syncthreads();
    cur ^= 1;
  }

  // residual + LN
#pragma unroll
  for (int i = 0; i < 2; ++i) {
#pragma unroll
    for (int r = 0; r < 4; ++r) {
      const int mloc = wm2 * 32 + i * 16 + quad * 4 + r;
      const long grow = (long)b * N_ + m0 + mloc;
      float s = 0.f, q = 0.f;
#pragma unroll
      for (int j = 0; j < 4; ++j) {
        const int c = wn2 * 64 + j * 16 + l15;
        float v = acc2[i][j][r] + bf2f(resb[grow * H_ + c]);
        acc2[i][j][r] = v;
        s += v; q += v * v;
      }
#pragma unroll
      for (int off = 1; off < 16; off <<= 1) {
        s += __shfl_xor(s, off);
        q += __shfl_xor(q, off);
      }
      if (l15 == 0) { red[wn2][mloc][0] = s; red[wn2][mloc][1] = q; }
    }
  }
  __syncthreads();
#pragma unroll
  for (int i = 0; i < 2; ++i) {
#pragma unroll
    for (int r = 0; r < 4; ++r) {
      const int mloc = wm2 * 32 + i * 16 + quad * 4 + r;
      const long grow = (long)b * N_ + m0 + mloc;
      float S = red[0][mloc][0] + red[1][mloc][0] + red[2][mloc][0] + red[3][mloc][0];
      float Q = red[0][mloc][1] + red[1][mloc][1] + red[2][mloc][1] + red[3][mloc][1];
      float mu = S * (1.f / H_);
      float var = Q * (1.f / H_) - mu * mu;
      float inv = 1.f / sqrtf(var + EPSF);
#pragma unroll
      for (int j = 0; j < 4; ++j) {
        const int c = wn2 * 64 + j * 16 + l15;
        float o = (acc2[i][j][r] - mu) * inv;
        post[grow * H_ + c] = o;
        postb[grow * H_ + c] = f2bf(o);
      }
    }
  }
}

// ========== Fused FFN: x = LN(relu(post@W1^T+b1)@W2^T + b2 + post), out = mask*x ==========
// 64 rows per block, 512 threads (8 waves, 2x4). t1 lives in LDS between phases.
// Both K-loops: double-buffered LDS, prefetch next tile, ONE barrier per step.
// LAST=0: out f_bf bf16; LAST=1: out out_x fp32.
template<int LAST>
__global__ __launch_bounds__(512) void ffn_k(
    const unsigned short* __restrict__ postb, const float* __restrict__ postf,
    const unsigned short* __restrict__ w1, const float* __restrict__ b1,
    const unsigned short* __restrict__ w2, const float* __restrict__ b2,
    const float* __restrict__ masks,
    unsigned short* __restrict__ fb, float* __restrict__ outx) {
  __shared__ __align__(16) unsigned short As[2][64 * 32];    // 8 KB
  __shared__ __align__(16) unsigned short Bs[2][256 * 32];   // 32 KB
  __shared__ __align__(16) unsigned short T1[64 * 264];      // 33 KB, padded rows
  __shared__ float red[4][64][2];                            // 2 KB
  const int t = threadIdx.x;
  const int wave = t >> 6, lane = t & 63;
  const int wm = wave >> 2, wn = wave & 3;
  const int quad = lane >> 4, l15 = lane & 15;
  const int m0 = blockIdx.y * 64;
  const int srow = lane >> 2;
  const int kc = KC_STAGE(lane);
  const int pos8 = (lane & 3) * 8;
  const int soff = KC_READ(quad, l15);

  const unsigned short* pa = postb + (size_t)(m0 + wave * 16 + srow) * H_ + kc;  // waves 0..3
  const int lao = (wave * 16 + srow) * 32 + pos8;
  const int lbo = (wave * 16 + srow) * 32 + pos8;   // rows 0..127; +128*32 for rows 128..255

  const unsigned short* qb0 = w2 + (size_t)(wave * 16 + srow) * H_ + kc;  // phase-2 B pointers
  const unsigned short* qb1 = qb0 + (size_t)128 * H_;

  // ---- Phase 1: t1 = relu(post @ W1^T + b1) -> T1 (LDS) ----
  {
    const unsigned short* pb0 = w1 + (size_t)(wave * 16 + srow) * H_ + kc;
    const unsigned short* pb1 = pb0 + (size_t)128 * H_;
    f32x4 acc[2][4];
#pragma unroll
    for (int i = 0; i < 2; ++i)
#pragma unroll
      for (int j = 0; j < 4; ++j) acc[i][j] = (f32x4){0.f, 0.f, 0.f, 0.f};
    // prologue
    if (wave < 4) async16(pa, &As[0][lao]);
    async16(pb0, &Bs[0][lbo]);
    async16(pb1, &Bs[0][lbo + 128 * 32]);
    __syncthreads();
    int cur = 0;
#pragma unroll
    for (int tt = 0; tt < 8; ++tt) {
      if (tt < 7) {
        const int kn = (tt + 1) * 32;
        if (wave < 4) async16(pa + kn, &As[cur ^ 1][lao]);
        async16(pb0 + kn, &Bs[cur ^ 1][lbo]);
        async16(pb1 + kn, &Bs[cur ^ 1][lbo + 128 * 32]);
      }
      bf16x8 af[2], bfr[4];
#pragma unroll
      for (int i = 0; i < 2; ++i)
        af[i] = *(const bf16x8*)&As[cur][(wm * 32 + i * 16 + l15) * 32 + soff];
#pragma unroll
      for (int j = 0; j < 4; ++j)
        bfr[j] = *(const bf16x8*)&Bs[cur][(wn * 64 + j * 16 + l15) * 32 + soff];
#pragma unroll
      for (int i = 0; i < 2; ++i)
#pragma unroll
        for (int j = 0; j < 4; ++j)
          acc[i][j] = __builtin_amdgcn_mfma_f32_16x16x32_bf16(af[i], bfr[j], acc[i][j], 0, 0, 0);
      __syncthreads();
      cur ^= 1;
    }

    // early stage of phase-2 W2 tile 0 into Bs[0]; hidden under bias/relu/T1 epilogue
    async16(qb0, &Bs[0][lbo]);
    async16(qb1, &Bs[0][lbo + 128 * 32]);

    float bv[4];
#pragma unroll
    for (int j = 0; j < 4; ++j) bv[j] = b1[wn * 64 + j * 16 + l15];
#pragma unroll
    for (int i = 0; i < 2; ++i) {
#pragma unroll
      for (int r = 0; r < 4; ++r) {
        const int mloc = wm * 32 + i * 16 + quad * 4 + r;
#pragma unroll
        for (int j = 0; j < 4; ++j) {
          const int c = wn * 64 + j * 16 + l15;
          T1[mloc * 264 + c] = f2bf(fmaxf(acc[i][j][r] + bv[j], 0.f));
        }
      }
    }
  }
  __syncthreads();   // T1 visible + W2 tile-0 staged (vmcnt drained)

  // ---- Phase 2: x = LN(T1 @ W2^T + b2 + post) * mask ----
  {
    f32x4 acc[2][4];
#pragma unroll
    for (int i = 0; i < 2; ++i)
#pragma unroll
      for (int j = 0; j < 4; ++j) acc[i][j] = (f32x4){0.f, 0.f, 0.f, 0.f};
    int cur = 0;   // W2 tile 0 already in Bs[0]
#pragma unroll
    for (int tt = 0; tt < 8; ++tt) {
      if (tt < 7) {
        const int kn = (tt + 1) * 32;
        async16(qb0 + kn, &Bs[cur ^ 1][lbo]);
        async16(qb1 + kn, &Bs[cur ^ 1][lbo + 128 * 32]);
      }
      bf16x8 af[2], bfr[4];
#pragma unroll
      for (int i = 0; i < 2; ++i)
        af[i] = *(const bf16x8*)&T1[(wm * 32 + i * 16 + l15) * 264 + tt * 32 + quad * 8];
#pragma unroll
      for (int j = 0; j < 4; ++j)
        bfr[j] = *(const bf16x8*)&Bs[cur][(wn * 64 + j * 16 + l15) * 32 + soff];
#pragma unroll
      for (int i = 0; i < 2; ++i)
#pragma unroll
        for (int j = 0; j < 4; ++j)
          acc[i][j] = __builtin_amdgcn_mfma_f32_16x16x32_bf16(af[i], bfr[j], acc[i][j], 0, 0, 0);
      __syncthreads();
      cur ^= 1;
    }
    float bv[4];
#pragma unroll
    for (int j = 0; j < 4; ++j) bv[j] = b2[wn * 64 + j * 16 + l15];
#pragma unroll
    for (int i = 0; i < 2; ++i) {
#pragma unroll
      for (int r = 0; r < 4; ++r) {
        const int mloc = wm * 32 + i * 16 + quad * 4 + r;
        const long grow = (long)m0 + mloc;
        float s = 0.f, q = 0.f;
#pragma unroll
        for (int j = 0; j < 4; ++j) {
          const int c = wn * 64 + j * 16 + l15;
          float v = acc[i][j][r] + bv[j] + postf[grow * H_ + c];
          acc[i][j][r] = v;
          s += v; q += v * v;
        }
#pragma unroll
        for (int off = 1; off < 16; off <<= 1) {
          s += __shfl_xor(s, off);
          q += __shfl_xor(q, off);
        }
        if (l15 == 0) { red[wn][mloc][0] = s; red[wn][mloc][1] = q; }
      }
    }
    __syncthreads();
#pragma unroll
    for (int i = 0; i < 2; ++i) {
#pragma unroll
      for (int r = 0; r < 4; ++r) {
        const int mloc = wm * 32 + i * 16 + quad * 4 + r;
        const long grow = (long)m0 + mloc;
        float S = red[0][mloc][0] + red[1][mloc][0] + red[2][mloc][0] + red[3][mloc][0];
        float Q = red[0][mloc][1] + red[1][mloc][1] + red[2][mloc][1] + red[3][mloc][1];
        float mu = S * (1.f / H_);
        float var = Q * (1.f / H_) - mu * mu;
        float inv = 1.f / sqrtf(var + EPSF);
        float mval = masks[grow];
#pragma unroll
        for (int j = 0; j < 4; ++j) {
          const int c = wn * 64 + j * 16 + l15;
          float o = (acc[i][j][r] - mu) * inv * mval;
          if (LAST) outx[grow * H_ + c] = o;
          else      fb[grow * H_ + c] = f2bf(o);
        }
      }
    }
  }
}

extern "C" void kernel_launch(void* const* d_in, const int* in_sizes, int n_in,
                              void* d_out, int out_size, void* d_ws, size_t ws_size,
                              hipStream_t stream) {
  const float* features = (const float*)d_in[0];
  const float* masks    = (const float*)d_in[1];
  const float* guide    = (const float*)d_in[2];
  const float* prior    = (const float*)d_in[3];
  const float* WQ       = (const float*)d_in[4];
  const float* WK       = (const float*)d_in[5];
  const float* WV       = (const float*)d_in[6];
  const float* W1       = (const float*)d_in[7];
  const float* b1       = (const float*)d_in[8];
  const float* W2       = (const float*)d_in[9];
  const float* b2       = (const float*)d_in[10];

  float* out     = (float*)d_out;
  float* out_x   = out;
  float* out_att = out + (size_t)BN_ * H_;

  char* w = (char*)d_ws;
  float* post = (float*)w;                     w += (size_t)BN_ * H_ * 4;        // 16 MB
  unsigned short* f_bf   = (unsigned short*)w; w += (size_t)BN_ * H_ * 2;        // 8 MB
  unsigned short* qk_bf  = (unsigned short*)w; w += (size_t)BN_ * 2 * H_ * 2;    // 16 MB
  unsigned short* post_bf= (unsigned short*)w; w += (size_t)BN_ * H_ * 2;        // 8 MB
  unsigned short* vT     = (unsigned short*)w; w += (size_t)BN_ * H_ * 2;        // 8 MB
  unsigned short* wqk_bf = (unsigned short*)w; w += (size_t)S_ * 2 * HH_ * 2;
  unsigned short* wv_bf  = (unsigned short*)w; w += (size_t)S_ * HH_ * 2;
  unsigned short* w1_bf  = (unsigned short*)w; w += (size_t)S_ * HH_ * 2;
  unsigned short* w2_bf  = (unsigned short*)w; w += (size_t)S_ * HH_ * 2;

  dim3 g_cvt(5 * S_ * HH_ / 1024);
  dim3 g_ew(BN_ * H_ / 1024);
  dim3 g_qkp(4, BN_ / 128, 1);                 // QK fused proj: Nn=512
  dim3 g_vt(4, 2, B_);                         // vT: Nn=512, M=256 (h), per batch
  dim3 g_ls(B_, N_ / 64, 1);                   // fused logits/softmax + PV + LN (batch-major for XCD/L2 locality)
  dim3 g_ffn(1, BN_ / 64, 1);                  // fused FFN + LN

  cvt_all_k<<<g_cvt, 256, 0, stream>>>(WQ, WK, WV, W1, W2, wqk_bf, wv_bf, w1_bf, w2_bf);
  mask_mul_k<<<g_ew, 256, 0, stream>>>(features, masks, f_bf);

  const long sF  = (long)N_ * H_;
  const long sVT = (long)H_ * N_;

  for (int i = 0; i < S_; ++i) {
    float* att = out_att + (size_t)i * B_ * N_ * N_;
    // vT[b][h][n] = WV[i] @ f[b]^T
    mfma_gemm_k<<<g_vt, 256, 0, stream>>>(wv_bf + (size_t)i * HH_, f_bf, vT,
                                          H_, N_, H_, H_, 0, sF, sVT);
    if (i == 0) {
      ls_pv_k<1><<<g_ls, 512, 0, stream>>>(nullptr, prior, nullptr, nullptr,
                                           vT, f_bf, att, post, post_bf);
    } else {
      // qk = f @ [WQ;WK]^T -> bf16 [BN][512]
      mfma_gemm_k<<<g_qkp, 256, 0, stream>>>(f_bf, wqk_bf + (size_t)i * 2 * HH_, qk_bf,
                                             H_, 2 * H_, H_, H_, 0, 0, 0);
      ls_pv_k<0><<<g_ls, 512, 0, stream>>>(qk_bf, nullptr, masks, guide,
                                           vT, f_bf, att, post, post_bf);
    }
    if (i < S_ - 1) {
      ffn_k<0><<<g_ffn, 512, 0, stream>>>(post_bf, post,
          w1_bf + (size_t)i * HH_, b1 + (size_t)i * H_,
          w2_bf + (size_t)i * HH_, b2 + (size_t)i * H_, masks, f_bf, nullptr);
    } else {
      ffn_k<1><<<g_ffn, 512, 0, stream>>>(post_bf, post,
          w1_bf + (size_t)i * HH_, b1 + (size_t)i * H_,
          w2_bf + (size_t)i * HH_, b2 + (size_t)i * H_, masks, nullptr, out_x);
    }
  }
}